// Round 1
// baseline (636.092 us; speedup 1.0000x reference)
//
#include <hip/hip_runtime.h>
#include <math.h>

#define L_DIM 2048
#define S_DIM 2048
#define E_DIM 2048
#define H_DIM 16
#define D_HEAD 128

using bf16x8 = __attribute__((ext_vector_type(8))) short;  // 8 bf16 in 4 VGPRs
using f32x4  = __attribute__((ext_vector_type(4))) float;  // MFMA C/D frag

// Pack two fp32 -> two bf16 (round-half-up) in one v_perm after two adds.
__device__ __forceinline__ unsigned pack2_bf16(float a, float b) {
  unsigned ua = __builtin_bit_cast(unsigned, a) + 0x8000u;
  unsigned ub = __builtin_bit_cast(unsigned, b) + 0x8000u;
  // bytes 0-1 from ua hi16, bytes 2-3 from ub hi16
  return __builtin_amdgcn_perm(ub, ua, 0x07060302u);
}
__device__ __forceinline__ unsigned short f2bf(float a) {
  unsigned u = __builtin_bit_cast(unsigned, a) + 0x8000u;
  return (unsigned short)(u >> 16);
}

// ---------------------------------------------------------------------------
// GEMM-NT: C[m,n] = sum_k A[m,k]*B[n,k] (+bias, epilogue variants)
// MODE 0: QKV projection, blockIdx.z in {0,1,2} selects (A, W-slice, out).
//         z=0 -> qb bf16 (L,E); z=1 -> kb bf16 (S,E); z=2 -> vt bf16 TRANSPOSED (E,S)
// MODE 1: out-projection, fp32 out with residual: X = acc + bias + Res
// 128x128 tile, BK=32, 256 threads (4 waves, 2x2 of 64x64), 16x16x32 bf16 MFMA.
// ---------------------------------------------------------------------------
#define GBM 128
#define GBN 128
#define GBK 32
#define GLD 40   // padded LDS k-stride (shorts): 80B rows keep 16B alignment, 2-way banks

template<int MODE>
__global__ __launch_bounds__(256, 2)
void gemm_nt(const float* __restrict__ Aq, const float* __restrict__ Ak,
             const float* __restrict__ Av, const float* __restrict__ Bmat,
             const float* __restrict__ bias0,
             unsigned short* __restrict__ qb, unsigned short* __restrict__ kb,
             unsigned short* __restrict__ vt,
             const float* __restrict__ Res, float* __restrict__ Xout)
{
  __shared__ unsigned short As[GBM * GLD];
  __shared__ unsigned short Bs[GBN * GLD];
  const int tid  = threadIdx.x;
  const int lane = tid & 63;
  const int wave = tid >> 6;
  const int quad = lane >> 4;
  const int c16  = lane & 15;
  const int m0 = blockIdx.y * GBM;
  const int n0 = blockIdx.x * GBN;
  const int z  = blockIdx.z;

  const float* A;
  const float* B;
  const float* bias;
  if (MODE == 0) {
    A = (z == 0) ? Aq : (z == 1) ? Ak : Av;
    B = Bmat + (size_t)z * E_DIM * E_DIM;
    bias = bias0 + z * E_DIM;
  } else {
    A = Aq; B = Bmat; bias = bias0;
  }

  f32x4 acc[4][4];
#pragma unroll
  for (int i = 0; i < 4; i++)
#pragma unroll
    for (int j = 0; j < 4; j++) acc[i][j] = (f32x4){0.f, 0.f, 0.f, 0.f};

  const int wm = (wave >> 1) * 64;
  const int wn = (wave & 1) * 64;

  for (int k0 = 0; k0 < E_DIM; k0 += GBK) {
    // stage 128x32 fp32 tiles of A and B -> bf16 LDS (16 el each per thread)
#pragma unroll
    for (int i = 0; i < 4; i++) {
      int f   = tid + 256 * i;
      int row = f >> 3;
      int col = (f & 7) * 4;
      float4 va = *(const float4*)(A + (size_t)(m0 + row) * E_DIM + k0 + col);
      float4 vb = *(const float4*)(B + (size_t)(n0 + row) * E_DIM + k0 + col);
      unsigned* pa = (unsigned*)&As[row * GLD + col];
      pa[0] = pack2_bf16(va.x, va.y);
      pa[1] = pack2_bf16(va.z, va.w);
      unsigned* pb = (unsigned*)&Bs[row * GLD + col];
      pb[0] = pack2_bf16(vb.x, vb.y);
      pb[1] = pack2_bf16(vb.z, vb.w);
    }
    __syncthreads();
    bf16x8 af[4], bfr[4];
#pragma unroll
    for (int t = 0; t < 4; t++) {
      // A frag: m = c16, k = quad*8+j (16B-aligned: GLD*2 = 80 = 5*16)
      af[t]  = *(const bf16x8*)&As[(wm + t * 16 + c16) * GLD + quad * 8];
      bfr[t] = *(const bf16x8*)&Bs[(wn + t * 16 + c16) * GLD + quad * 8];
    }
#pragma unroll
    for (int tm = 0; tm < 4; tm++)
#pragma unroll
      for (int tn = 0; tn < 4; tn++)
        acc[tm][tn] = __builtin_amdgcn_mfma_f32_16x16x32_bf16(af[tm], bfr[tn],
                                                              acc[tm][tn], 0, 0, 0);
    __syncthreads();
  }

  // epilogue: C/D layout col = c16 (n), row = quad*4 + r (m)
  float bv[4];
#pragma unroll
  for (int tn = 0; tn < 4; tn++) bv[tn] = bias[n0 + wn + tn * 16 + c16];

  if (MODE == 1) {
#pragma unroll
    for (int tm = 0; tm < 4; tm++) {
      int mr = m0 + wm + tm * 16 + quad * 4;
#pragma unroll
      for (int tn = 0; tn < 4; tn++) {
        int n = n0 + wn + tn * 16 + c16;
#pragma unroll
        for (int r = 0; r < 4; r++) {
          size_t idx = (size_t)(mr + r) * E_DIM + n;
          Xout[idx] = acc[tm][tn][r] + bv[tn] + Res[idx];
        }
      }
    }
  } else if (z < 2) {
    unsigned short* O = (z == 0) ? qb : kb;
#pragma unroll
    for (int tm = 0; tm < 4; tm++) {
      int mr = m0 + wm + tm * 16 + quad * 4;
#pragma unroll
      for (int tn = 0; tn < 4; tn++) {
        int n = n0 + wn + tn * 16 + c16;
#pragma unroll
        for (int r = 0; r < 4; r++)
          O[(size_t)(mr + r) * E_DIM + n] = f2bf(acc[tm][tn][r] + bv[tn]);
      }
    }
  } else {
    // V transposed: vt[(h*128+d)][s] so flash PV B-frags are contiguous.
    // 4 acc rows (same n, consecutive m) pack into one 8B store.
#pragma unroll
    for (int tm = 0; tm < 4; tm++) {
      int mr = m0 + wm + tm * 16 + quad * 4;
#pragma unroll
      for (int tn = 0; tn < 4; tn++) {
        int n = n0 + wn + tn * 16 + c16;
        uint2 pv;
        pv.x = pack2_bf16(acc[tm][tn][0] + bv[tn], acc[tm][tn][1] + bv[tn]);
        pv.y = pack2_bf16(acc[tm][tn][2] + bv[tn], acc[tm][tn][3] + bv[tn]);
        *(uint2*)(vt + (size_t)n * S_DIM + mr) = pv;
      }
    }
  }
}

// ---------------------------------------------------------------------------
// time_bias[h][s] = dot(time_emb[s,:], tp_w[h,:]) + tp_b[h]. One wave per s.
// ---------------------------------------------------------------------------
__global__ __launch_bounds__(256)
void time_bias_kernel(const float* __restrict__ temb, const float* __restrict__ tpw,
                      const float* __restrict__ tpb, float* __restrict__ tb)
{
  const int lane = threadIdx.x & 63;
  const int wave = threadIdx.x >> 6;
  const int s = blockIdx.x * 4 + wave;
  float acc[16];
#pragma unroll
  for (int hh = 0; hh < 16; hh++) acc[hh] = 0.f;
  for (int i = 0; i < 32; i++) {
    int e = lane + i * 64;
    float t = temb[(size_t)s * E_DIM + e];
#pragma unroll
    for (int hh = 0; hh < 16; hh++)
      acc[hh] = fmaf(t, tpw[hh * E_DIM + e], acc[hh]);
  }
#pragma unroll
  for (int hh = 0; hh < 16; hh++) {
#pragma unroll
    for (int d = 1; d < 64; d <<= 1)
      acc[hh] += __shfl_xor(acc[hh], d, 64);
  }
#pragma unroll
  for (int hh = 0; hh < 16; hh++)
    if (lane == hh) tb[(size_t)hh * S_DIM + s] = acc[hh] + tpb[hh];
}

// ---------------------------------------------------------------------------
// Flash attention: one block = (head, 128 q-rows), 512 threads = 8 waves,
// each wave owns 16 q-rows. KV chunks of 64. Online softmax in registers
// (row stats shuffle-reduced across the 16 lanes of each quad). P goes
// through LDS to convert C/D layout -> A layout (m120 pattern).
// LDS: Ks 64x136 + Vs 128x72 + Ps 128x72 + bias = 54.5 KB.
// ---------------------------------------------------------------------------
__global__ __launch_bounds__(512, 2)
void flash_attn(const unsigned short* __restrict__ qb,
                const unsigned short* __restrict__ kb,
                const unsigned short* __restrict__ vt,
                const float* __restrict__ tb,
                float* __restrict__ ctx)
{
  __shared__ unsigned short Ks[64][136];   // [s_local][d]   (+8 pad)
  __shared__ unsigned short Vs[128][72];   // [d][s_local]   (V^T chunk)
  __shared__ unsigned short Ps[128][72];   // [l_local][s_local]
  __shared__ float bias_s[64];

  const int tid  = threadIdx.x;
  const int lane = tid & 63;
  const int wave = tid >> 6;
  const int quad = lane >> 4;
  const int c16  = lane & 15;
  const int h     = blockIdx.y;
  const int q0    = blockIdx.x * 128;
  const int lrow0 = q0 + wave * 16;

  // Q A-frags, resident for the whole block: Q[l = c16][k_d = quad*8+j]
  bf16x8 qf[4];
#pragma unroll
  for (int kd = 0; kd < 4; kd++)
    qf[kd] = *(const bf16x8*)(qb + (size_t)(lrow0 + c16) * E_DIM + h * D_HEAD
                              + kd * 32 + quad * 8);

  f32x4 of[8];
#pragma unroll
  for (int i = 0; i < 8; i++) of[i] = (f32x4){0.f, 0.f, 0.f, 0.f};
  float mi[4] = {-INFINITY, -INFINITY, -INFINITY, -INFINITY};
  float li[4] = {0.f, 0.f, 0.f, 0.f};
  const float scale = 0.08838834764831845f;   // 1/sqrt(128)
  const float log2e = 1.4426950408889634f;

  for (int s0 = 0; s0 < S_DIM; s0 += 64) {
    __syncthreads();   // previous chunk's Ks/Vs consumers done
#pragma unroll
    for (int i = 0; i < 2; i++) {            // K chunk: 64 x 128
      int f = tid + 512 * i;
      int row = f >> 4;
      int c8 = (f & 15) * 8;
      *(bf16x8*)&Ks[row][c8] =
          *(const bf16x8*)(kb + (size_t)(s0 + row) * E_DIM + h * D_HEAD + c8);
    }
#pragma unroll
    for (int i = 0; i < 2; i++) {            // V^T chunk: 128 x 64
      int f = tid + 512 * i;
      int row = f >> 3;
      int c8 = (f & 7) * 8;
      *(bf16x8*)&Vs[row][c8] =
          *(const bf16x8*)(vt + (size_t)(h * D_HEAD + row) * S_DIM + s0 + c8);
    }
    if (tid < 64) bias_s[tid] = tb[(size_t)h * S_DIM + s0 + tid];
    __syncthreads();

    // QK^T: sc[tn] covers s = tn*16 + c16, rows l = quad*4 + r
    f32x4 sc[4];
#pragma unroll
    for (int tn = 0; tn < 4; tn++) sc[tn] = (f32x4){0.f, 0.f, 0.f, 0.f};
#pragma unroll
    for (int tn = 0; tn < 4; tn++)
#pragma unroll
      for (int kd = 0; kd < 4; kd++) {
        bf16x8 kf = *(const bf16x8*)&Ks[tn * 16 + c16][kd * 32 + quad * 8];
        sc[tn] = __builtin_amdgcn_mfma_f32_16x16x32_bf16(qf[kd], kf, sc[tn], 0, 0, 0);
      }

#pragma unroll
    for (int tn = 0; tn < 4; tn++) {
      float bb = bias_s[tn * 16 + c16];
#pragma unroll
      for (int r = 0; r < 4; r++) sc[tn][r] = sc[tn][r] * scale + bb;
    }

    // online softmax per row (row stats live in the 16 lanes of each quad)
#pragma unroll
    for (int r = 0; r < 4; r++) {
      float m = fmaxf(fmaxf(sc[0][r], sc[1][r]), fmaxf(sc[2][r], sc[3][r]));
      m = fmaxf(m, __shfl_xor(m, 1, 64));
      m = fmaxf(m, __shfl_xor(m, 2, 64));
      m = fmaxf(m, __shfl_xor(m, 4, 64));
      m = fmaxf(m, __shfl_xor(m, 8, 64));
      float mn = fmaxf(mi[r], m);
      float al = exp2f((mi[r] - mn) * log2e);
      float rs = 0.f;
#pragma unroll
      for (int tn = 0; tn < 4; tn++) {
        float p = exp2f((sc[tn][r] - mn) * log2e);
        sc[tn][r] = p;
        rs += p;
      }
      rs += __shfl_xor(rs, 1, 64);
      rs += __shfl_xor(rs, 2, 64);
      rs += __shfl_xor(rs, 4, 64);
      rs += __shfl_xor(rs, 8, 64);
      li[r] = li[r] * al + rs;
      mi[r] = mn;
#pragma unroll
      for (int td = 0; td < 8; td++) of[td][r] *= al;
    }

    // P: C/D layout -> LDS (wave-private rows, no barrier needed)
#pragma unroll
    for (int tn = 0; tn < 4; tn++)
#pragma unroll
      for (int r = 0; r < 4; r++)
        Ps[wave * 16 + quad * 4 + r][tn * 16 + c16] = f2bf(sc[tn][r]);

    // PV: A = P (m=l, k=s), B = V^T (n=d, k=s)
#pragma unroll
    for (int ks = 0; ks < 2; ks++) {
      bf16x8 ap = *(const bf16x8*)&Ps[wave * 16 + c16][ks * 32 + quad * 8];
#pragma unroll
      for (int td = 0; td < 8; td++) {
        bf16x8 vf = *(const bf16x8*)&Vs[td * 16 + c16][ks * 32 + quad * 8];
        of[td] = __builtin_amdgcn_mfma_f32_16x16x32_bf16(ap, vf, of[td], 0, 0, 0);
      }
    }
  }

#pragma unroll
  for (int r = 0; r < 4; r++) {
    float rli = 1.0f / li[r];
    size_t lrow = lrow0 + quad * 4 + r;
#pragma unroll
    for (int td = 0; td < 8; td++)
      ctx[lrow * E_DIM + h * D_HEAD + td * 16 + c16] = of[td][r] * rli;
  }
}

// ---------------------------------------------------------------------------
// LayerNorm over rows of x (fp32), eps=1e-5
// ---------------------------------------------------------------------------
__global__ __launch_bounds__(256)
void layernorm_kernel(const float* __restrict__ x, const float* __restrict__ g,
                      const float* __restrict__ b, float* __restrict__ out)
{
  const int row = blockIdx.x;
  const int tid = threadIdx.x;
  const int lane = tid & 63, wave = tid >> 6;
  const float* xr = x + (size_t)row * E_DIM;
  float4 v0 = *(const float4*)(xr + tid * 4);
  float4 v1 = *(const float4*)(xr + 1024 + tid * 4);
  float s  = v0.x + v0.y + v0.z + v0.w + v1.x + v1.y + v1.z + v1.w;
  float ss = v0.x*v0.x + v0.y*v0.y + v0.z*v0.z + v0.w*v0.w
           + v1.x*v1.x + v1.y*v1.y + v1.z*v1.z + v1.w*v1.w;
#pragma unroll
  for (int d = 1; d < 64; d <<= 1) {
    s  += __shfl_xor(s, d, 64);
    ss += __shfl_xor(ss, d, 64);
  }
  __shared__ float red[8];
  if (lane == 0) { red[wave] = s; red[wave + 4] = ss; }
  __syncthreads();
  s  = red[0] + red[1] + red[2] + red[3];
  ss = red[4] + red[5] + red[6] + red[7];
  float mu   = s * (1.f / E_DIM);
  float var  = ss * (1.f / E_DIM) - mu * mu;
  float rstd = rsqrtf(var + 1e-5f);

  float4 g0 = *(const float4*)(g + tid * 4);
  float4 b0 = *(const float4*)(b + tid * 4);
  float4 g1 = *(const float4*)(g + 1024 + tid * 4);
  float4 b1 = *(const float4*)(b + 1024 + tid * 4);
  float4 o0, o1;
  o0.x = (v0.x - mu) * rstd * g0.x + b0.x;
  o0.y = (v0.y - mu) * rstd * g0.y + b0.y;
  o0.z = (v0.z - mu) * rstd * g0.z + b0.z;
  o0.w = (v0.w - mu) * rstd * g0.w + b0.w;
  o1.x = (v1.x - mu) * rstd * g1.x + b1.x;
  o1.y = (v1.y - mu) * rstd * g1.y + b1.y;
  o1.z = (v1.z - mu) * rstd * g1.z + b1.z;
  o1.w = (v1.w - mu) * rstd * g1.w + b1.w;
  *(float4*)(out + (size_t)row * E_DIM + tid * 4) = o0;
  *(float4*)(out + (size_t)row * E_DIM + 1024 + tid * 4) = o1;
}

extern "C" void kernel_launch(void* const* d_in, const int* in_sizes, int n_in,
                              void* d_out, int out_size, void* d_ws, size_t ws_size,
                              hipStream_t stream) {
  const float* query     = (const float*)d_in[0];
  const float* key       = (const float*)d_in[1];
  const float* value     = (const float*)d_in[2];
  const float* time_emb  = (const float*)d_in[3];
  const float* in_proj_w = (const float*)d_in[4];
  const float* in_proj_b = (const float*)d_in[5];
  const float* out_w     = (const float*)d_in[6];
  const float* out_b     = (const float*)d_in[7];
  const float* tp_w      = (const float*)d_in[8];
  const float* tp_b      = (const float*)d_in[9];
  const float* ln_g      = (const float*)d_in[10];
  const float* ln_b      = (const float*)d_in[11];

  char* ws = (char*)d_ws;
  size_t o = 0;
  unsigned short* qb = (unsigned short*)(ws + o); o += 8388608;   // (L,E) bf16
  unsigned short* kb = (unsigned short*)(ws + o); o += 8388608;   // (S,E) bf16
  unsigned short* vt = (unsigned short*)(ws + o); o += 8388608;   // (E,S) bf16 transposed
  float*          ctx = (float*)(ws + o);         o += 16777216;  // (L,E) fp32
  float*          xb  = (float*)(ws + o);         o += 16777216;  // (L,E) fp32 residual sum
  float*          tb  = (float*)(ws + o);         o += 131072;    // (H,S) fp32

  // 1) QKV projection (z selects q/k/v; V stored transposed)
  gemm_nt<0><<<dim3(16, 16, 3), 256, 0, stream>>>(query, key, value, in_proj_w,
                                                  in_proj_b, qb, kb, vt,
                                                  nullptr, nullptr);
  // 2) per-head time bias
  time_bias_kernel<<<512, 256, 0, stream>>>(time_emb, tp_w, tp_b, tb);
  // 3) flash attention -> ctx
  flash_attn<<<dim3(16, 16), 512, 0, stream>>>(qb, kb, vt, tb, ctx);
  // 4) out projection + residual -> xb
  gemm_nt<1><<<dim3(16, 16, 1), 256, 0, stream>>>(ctx, nullptr, nullptr, out_w,
                                                  out_b, nullptr, nullptr, nullptr,
                                                  query, xb);
  // 5) LayerNorm -> d_out
  layernorm_kernel<<<2048, 256, 0, stream>>>(xb, ln_g, ln_b, (float*)d_out);
}

// Round 2
// 398.674 us; speedup vs baseline: 1.5955x; 1.5955x over previous
//
#include <hip/hip_runtime.h>
#include <math.h>

#define L_DIM 2048
#define S_DIM 2048
#define E_DIM 2048
#define H_DIM 16
#define D_HEAD 128

using bf16x8 = __attribute__((ext_vector_type(8))) short;  // 8 bf16 in 4 VGPRs
using f32x4  = __attribute__((ext_vector_type(4))) float;  // MFMA C/D frag

// Pack two fp32 -> two bf16 (round-half-up) in one v_perm after two adds.
__device__ __forceinline__ unsigned pack2_bf16(float a, float b) {
  unsigned ua = __builtin_bit_cast(unsigned, a) + 0x8000u;
  unsigned ub = __builtin_bit_cast(unsigned, b) + 0x8000u;
  return __builtin_amdgcn_perm(ub, ua, 0x07060302u);
}
__device__ __forceinline__ unsigned short f2bf(float a) {
  unsigned u = __builtin_bit_cast(unsigned, a) + 0x8000u;
  return (unsigned short)(u >> 16);
}

// async global->LDS, 16B per lane. LDS dst is wave-uniform base + lane*16.
__device__ __forceinline__ void gl_lds16(const unsigned short* g, unsigned short* l) {
  __builtin_amdgcn_global_load_lds(
      (const __attribute__((address_space(1))) void*)g,
      (__attribute__((address_space(3))) void*)l, 16, 0, 0);
}

// ---------------------------------------------------------------------------
// fp32 -> bf16 conversion, 7 slices of E*E elements:
// z: 0=query->qa 1=key->ka 2=value->va 3..5=in_proj_w->wqkv 6=out_w->wo
// ---------------------------------------------------------------------------
__global__ __launch_bounds__(256)
void convert_bf16(const float* __restrict__ q, const float* __restrict__ k,
                  const float* __restrict__ v, const float* __restrict__ w_in,
                  const float* __restrict__ w_out,
                  unsigned short* __restrict__ qa, unsigned short* __restrict__ ka,
                  unsigned short* __restrict__ va, unsigned short* __restrict__ wqkv,
                  unsigned short* __restrict__ wo)
{
  const int z = blockIdx.y;
  const float* src;
  unsigned short* dst;
  switch (z) {
    case 0: src = q; dst = qa; break;
    case 1: src = k; dst = ka; break;
    case 2: src = v; dst = va; break;
    case 3: src = w_in;           dst = wqkv;           break;
    case 4: src = w_in + 4194304; dst = wqkv + 4194304; break;
    case 5: src = w_in + 8388608; dst = wqkv + 8388608; break;
    default: src = w_out; dst = wo; break;
  }
  size_t i = ((size_t)blockIdx.x * 256 + threadIdx.x) * 8;
  float4 a = *(const float4*)(src + i);
  float4 b = *(const float4*)(src + i + 4);
  uint4 o;
  o.x = pack2_bf16(a.x, a.y);
  o.y = pack2_bf16(a.z, a.w);
  o.z = pack2_bf16(b.x, b.y);
  o.w = pack2_bf16(b.z, b.w);
  *(uint4*)(dst + i) = o;
}

// ---------------------------------------------------------------------------
// bf16 GEMM-NT, m97-style: C[m,n] = sum_k A[m,k]*B[n,k].
// global_load_lds width-16 staging into XOR-swizzled LDS:
//   tile = 8 groups of 16 rows; within a group, chunk(row m, 16B-col c) lives
//   at slot 4m + (c ^ sig(m)), sig(m) = (m ^ (m>>2)) & 3.
//   -> staging stays 64B-coalesced, ds_read_b128 frag reads conflict-free.
// MODE 0: QKV projection, z in {0,1,2}; z=2 writes V^T (E,S) bf16.
// MODE 1: out-projection, fp32 out + bias + residual.
// 128x128x32 tile, 256 threads (2x2 waves of 64x64), 16x16x32 bf16 MFMA.
// ---------------------------------------------------------------------------
#define GBM 128
#define GBN 128
#define GBK 32

template<int MODE>
__global__ __launch_bounds__(256, 2)
void gemm_bt(const unsigned short* __restrict__ Aq, const unsigned short* __restrict__ Ak,
             const unsigned short* __restrict__ Av, const unsigned short* __restrict__ Bmat,
             const float* __restrict__ bias0,
             unsigned short* __restrict__ qb, unsigned short* __restrict__ kb,
             unsigned short* __restrict__ vt,
             const float* __restrict__ Res, float* __restrict__ Xout)
{
  __shared__ unsigned short As[GBM * GBK];   // 8 KB, swizzled
  __shared__ unsigned short Bs[GBN * GBK];   // 8 KB, swizzled
  const int tid  = threadIdx.x;
  const int lane = tid & 63;
  const int wave = tid >> 6;
  const int quad = lane >> 4;
  const int c16  = lane & 15;
  const int m0 = blockIdx.y * GBM;
  const int n0 = blockIdx.x * GBN;
  const int z  = blockIdx.z;

  const unsigned short* A;
  const unsigned short* B;
  const float* bias;
  if (MODE == 0) {
    A = (z == 0) ? Aq : (z == 1) ? Ak : Av;
    B = Bmat + (size_t)z * E_DIM * E_DIM;
    bias = bias0 + z * E_DIM;
  } else {
    A = Aq; B = Bmat; bias = bias0;
  }

  // staging role: lane -> (row-in-group ar, swizzled col-chunk ac)
  const int ar = lane >> 2;
  const int sg = (ar ^ (ar >> 2)) & 3;
  const int ac = (lane & 3) ^ sg;
  const unsigned short* aG0 = A + (size_t)(m0 + wave * 16 + ar) * E_DIM + ac * 8;
  const unsigned short* aG1 = aG0 + (size_t)64 * E_DIM;
  const unsigned short* bG0 = B + (size_t)(n0 + wave * 16 + ar) * E_DIM + ac * 8;
  const unsigned short* bG1 = bG0 + (size_t)64 * E_DIM;
  unsigned short* aS0 = &As[wave * 512];
  unsigned short* aS1 = &As[(wave + 4) * 512];
  unsigned short* bS0 = &Bs[wave * 512];
  unsigned short* bS1 = &Bs[(wave + 4) * 512];

  // frag-read slot offset (shorts) within a group for (m=c16, colchunk=quad)
  const int sigm = (c16 ^ (c16 >> 2)) & 3;
  const int fr = (4 * c16 + (quad ^ sigm)) * 8;

  f32x4 acc[4][4];
#pragma unroll
  for (int i = 0; i < 4; i++)
#pragma unroll
    for (int j = 0; j < 4; j++) acc[i][j] = (f32x4){0.f, 0.f, 0.f, 0.f};

  const int wm = (wave >> 1) * 64;
  const int wn = (wave & 1) * 64;
  const int ga = (wm >> 4);     // A group base for this wave's rows
  const int gb = (wn >> 4);

  for (int k0 = 0; k0 < E_DIM; k0 += GBK) {
    __syncthreads();            // previous iteration's ds_reads complete
    gl_lds16(aG0, aS0);
    gl_lds16(aG1, aS1);
    gl_lds16(bG0, bS0);
    gl_lds16(bG1, bS1);
    aG0 += GBK; aG1 += GBK; bG0 += GBK; bG1 += GBK;
    __syncthreads();            // vmcnt(0) drain: LDS populated

    bf16x8 af[4], bfr[4];
#pragma unroll
    for (int t = 0; t < 4; t++) {
      af[t]  = *(const bf16x8*)&As[(ga + t) * 512 + fr];
      bfr[t] = *(const bf16x8*)&Bs[(gb + t) * 512 + fr];
    }
#pragma unroll
    for (int tm = 0; tm < 4; tm++)
#pragma unroll
      for (int tn = 0; tn < 4; tn++)
        acc[tm][tn] = __builtin_amdgcn_mfma_f32_16x16x32_bf16(af[tm], bfr[tn],
                                                              acc[tm][tn], 0, 0, 0);
  }

  // epilogue: C/D layout col = c16 (n), row = quad*4 + r (m)
  float bv[4];
#pragma unroll
  for (int tn = 0; tn < 4; tn++) bv[tn] = bias[n0 + wn + tn * 16 + c16];

  if (MODE == 1) {
#pragma unroll
    for (int tm = 0; tm < 4; tm++) {
      int mr = m0 + wm + tm * 16 + quad * 4;
#pragma unroll
      for (int tn = 0; tn < 4; tn++) {
        int n = n0 + wn + tn * 16 + c16;
#pragma unroll
        for (int r = 0; r < 4; r++) {
          size_t idx = (size_t)(mr + r) * E_DIM + n;
          Xout[idx] = acc[tm][tn][r] + bv[tn] + Res[idx];
        }
      }
    }
  } else if (z < 2) {
    unsigned short* O = (z == 0) ? qb : kb;
#pragma unroll
    for (int tm = 0; tm < 4; tm++) {
      int mr = m0 + wm + tm * 16 + quad * 4;
#pragma unroll
      for (int tn = 0; tn < 4; tn++) {
        int n = n0 + wn + tn * 16 + c16;
#pragma unroll
        for (int r = 0; r < 4; r++)
          O[(size_t)(mr + r) * E_DIM + n] = f2bf(acc[tm][tn][r] + bv[tn]);
      }
    }
  } else {
    // V^T: vt[(h*128+d)][s]; 4 acc rows (consecutive m = s) pack to one 8B store
#pragma unroll
    for (int tm = 0; tm < 4; tm++) {
      int mr = m0 + wm + tm * 16 + quad * 4;
#pragma unroll
      for (int tn = 0; tn < 4; tn++) {
        int n = n0 + wn + tn * 16 + c16;
        uint2 pv;
        pv.x = pack2_bf16(acc[tm][tn][0] + bv[tn], acc[tm][tn][1] + bv[tn]);
        pv.y = pack2_bf16(acc[tm][tn][2] + bv[tn], acc[tm][tn][3] + bv[tn]);
        *(uint2*)(vt + (size_t)n * S_DIM + mr) = pv;
      }
    }
  }
}

// ---------------------------------------------------------------------------
// time_bias[h][s] = dot(time_emb[s,:], tp_w[h,:]) + tp_b[h]. One wave per s.
// ---------------------------------------------------------------------------
__global__ __launch_bounds__(256)
void time_bias_kernel(const float* __restrict__ temb, const float* __restrict__ tpw,
                      const float* __restrict__ tpb, float* __restrict__ tb)
{
  const int lane = threadIdx.x & 63;
  const int wave = threadIdx.x >> 6;
  const int s = blockIdx.x * 4 + wave;
  float acc[16];
#pragma unroll
  for (int hh = 0; hh < 16; hh++) acc[hh] = 0.f;
  for (int i = 0; i < 32; i++) {
    int e = lane + i * 64;
    float t = temb[(size_t)s * E_DIM + e];
#pragma unroll
    for (int hh = 0; hh < 16; hh++)
      acc[hh] = fmaf(t, tpw[hh * E_DIM + e], acc[hh]);
  }
#pragma unroll
  for (int hh = 0; hh < 16; hh++) {
#pragma unroll
    for (int d = 1; d < 64; d <<= 1)
      acc[hh] += __shfl_xor(acc[hh], d, 64);
  }
#pragma unroll
  for (int hh = 0; hh < 16; hh++)
    if (lane == hh) tb[(size_t)hh * S_DIM + s] = acc[hh] + tpb[hh];
}

// ---------------------------------------------------------------------------
// Flash attention: one block = (head, 64 q-rows), 256 threads = 4 waves,
// each wave owns 16 q-rows. KV chunks of 64, online softmax in registers.
// ctx written as bf16 (feeds the bf16 out-projection GEMM).
// LDS: Ks 64x136 (17.4K) + Vs 128x72 (18.4K) + Ps 64x72 (9.2K) ~= 45 KB.
// ---------------------------------------------------------------------------
__global__ __launch_bounds__(256, 2)
void flash_attn(const unsigned short* __restrict__ qb,
                const unsigned short* __restrict__ kb,
                const unsigned short* __restrict__ vt,
                const float* __restrict__ tb,
                unsigned short* __restrict__ ctx)
{
  __shared__ unsigned short Ks[64][136];   // [s_local][d]   (+8 pad)
  __shared__ unsigned short Vs[128][72];   // [d][s_local]   (V^T chunk)
  __shared__ unsigned short Ps[64][72];    // [l_local][s_local]
  __shared__ float bias_s[64];

  const int tid  = threadIdx.x;
  const int lane = tid & 63;
  const int wave = tid >> 6;
  const int quad = lane >> 4;
  const int c16  = lane & 15;
  const int h     = blockIdx.y;
  const int lrow0 = blockIdx.x * 64 + wave * 16;

  bf16x8 qf[4];
#pragma unroll
  for (int kd = 0; kd < 4; kd++)
    qf[kd] = *(const bf16x8*)(qb + (size_t)(lrow0 + c16) * E_DIM + h * D_HEAD
                              + kd * 32 + quad * 8);

  f32x4 of[8];
#pragma unroll
  for (int i = 0; i < 8; i++) of[i] = (f32x4){0.f, 0.f, 0.f, 0.f};
  float mi[4] = {-INFINITY, -INFINITY, -INFINITY, -INFINITY};
  float li[4] = {0.f, 0.f, 0.f, 0.f};
  const float scale = 0.08838834764831845f;   // 1/sqrt(128)
  const float log2e = 1.4426950408889634f;

  for (int s0 = 0; s0 < S_DIM; s0 += 64) {
    __syncthreads();
#pragma unroll
    for (int i = 0; i < 4; i++) {            // K chunk: 64 x 128
      int f = tid + 256 * i;
      int row = f >> 4;
      int c8 = (f & 15) * 8;
      *(bf16x8*)&Ks[row][c8] =
          *(const bf16x8*)(kb + (size_t)(s0 + row) * E_DIM + h * D_HEAD + c8);
    }
#pragma unroll
    for (int i = 0; i < 4; i++) {            // V^T chunk: 128 x 64
      int f = tid + 256 * i;
      int row = f >> 3;
      int c8 = (f & 7) * 8;
      *(bf16x8*)&Vs[row][c8] =
          *(const bf16x8*)(vt + (size_t)(h * D_HEAD + row) * S_DIM + s0 + c8);
    }
    if (tid < 64) bias_s[tid] = tb[(size_t)h * S_DIM + s0 + tid];
    __syncthreads();

    f32x4 sc[4];
#pragma unroll
    for (int tn = 0; tn < 4; tn++) sc[tn] = (f32x4){0.f, 0.f, 0.f, 0.f};
#pragma unroll
    for (int tn = 0; tn < 4; tn++)
#pragma unroll
      for (int kd = 0; kd < 4; kd++) {
        bf16x8 kf = *(const bf16x8*)&Ks[tn * 16 + c16][kd * 32 + quad * 8];
        sc[tn] = __builtin_amdgcn_mfma_f32_16x16x32_bf16(qf[kd], kf, sc[tn], 0, 0, 0);
      }

#pragma unroll
    for (int tn = 0; tn < 4; tn++) {
      float bb = bias_s[tn * 16 + c16];
#pragma unroll
      for (int r = 0; r < 4; r++) sc[tn][r] = sc[tn][r] * scale + bb;
    }

#pragma unroll
    for (int r = 0; r < 4; r++) {
      float m = fmaxf(fmaxf(sc[0][r], sc[1][r]), fmaxf(sc[2][r], sc[3][r]));
      m = fmaxf(m, __shfl_xor(m, 1, 64));
      m = fmaxf(m, __shfl_xor(m, 2, 64));
      m = fmaxf(m, __shfl_xor(m, 4, 64));
      m = fmaxf(m, __shfl_xor(m, 8, 64));
      float mn = fmaxf(mi[r], m);
      float al = exp2f((mi[r] - mn) * log2e);
      float rs = 0.f;
#pragma unroll
      for (int tn = 0; tn < 4; tn++) {
        float p = exp2f((sc[tn][r] - mn) * log2e);
        sc[tn][r] = p;
        rs += p;
      }
      rs += __shfl_xor(rs, 1, 64);
      rs += __shfl_xor(rs, 2, 64);
      rs += __shfl_xor(rs, 4, 64);
      rs += __shfl_xor(rs, 8, 64);
      li[r] = li[r] * al + rs;
      mi[r] = mn;
#pragma unroll
      for (int td = 0; td < 8; td++) of[td][r] *= al;
    }

    // P: C/D layout -> LDS (wave-private rows, no barrier needed)
#pragma unroll
    for (int tn = 0; tn < 4; tn++)
#pragma unroll
      for (int r = 0; r < 4; r++)
        Ps[wave * 16 + quad * 4 + r][tn * 16 + c16] = f2bf(sc[tn][r]);

#pragma unroll
    for (int ks = 0; ks < 2; ks++) {
      bf16x8 ap = *(const bf16x8*)&Ps[wave * 16 + c16][ks * 32 + quad * 8];
#pragma unroll
      for (int td = 0; td < 8; td++) {
        bf16x8 vf = *(const bf16x8*)&Vs[td * 16 + c16][ks * 32 + quad * 8];
        of[td] = __builtin_amdgcn_mfma_f32_16x16x32_bf16(ap, vf, of[td], 0, 0, 0);
      }
    }
  }

#pragma unroll
  for (int r = 0; r < 4; r++) {
    float rli = 1.0f / li[r];
    size_t lrow = lrow0 + quad * 4 + r;
#pragma unroll
    for (int td = 0; td < 8; td++)
      ctx[lrow * E_DIM + h * D_HEAD + td * 16 + c16] = f2bf(of[td][r] * rli);
  }
}

// ---------------------------------------------------------------------------
// LayerNorm over rows of x (fp32), eps=1e-5
// ---------------------------------------------------------------------------
__global__ __launch_bounds__(256)
void layernorm_kernel(const float* __restrict__ x, const float* __restrict__ g,
                      const float* __restrict__ b, float* __restrict__ out)
{
  const int row = blockIdx.x;
  const int tid = threadIdx.x;
  const int lane = tid & 63, wave = tid >> 6;
  const float* xr = x + (size_t)row * E_DIM;
  float4 v0 = *(const float4*)(xr + tid * 4);
  float4 v1 = *(const float4*)(xr + 1024 + tid * 4);
  float s  = v0.x + v0.y + v0.z + v0.w + v1.x + v1.y + v1.z + v1.w;
  float ss = v0.x*v0.x + v0.y*v0.y + v0.z*v0.z + v0.w*v0.w
           + v1.x*v1.x + v1.y*v1.y + v1.z*v1.z + v1.w*v1.w;
#pragma unroll
  for (int d = 1; d < 64; d <<= 1) {
    s  += __shfl_xor(s, d, 64);
    ss += __shfl_xor(ss, d, 64);
  }
  __shared__ float red[8];
  if (lane == 0) { red[wave] = s; red[wave + 4] = ss; }
  __syncthreads();
  s  = red[0] + red[1] + red[2] + red[3];
  ss = red[4] + red[5] + red[6] + red[7];
  float mu   = s * (1.f / E_DIM);
  float var  = ss * (1.f / E_DIM) - mu * mu;
  float rstd = rsqrtf(var + 1e-5f);

  float4 g0 = *(const float4*)(g + tid * 4);
  float4 b0 = *(const float4*)(b + tid * 4);
  float4 g1 = *(const float4*)(g + 1024 + tid * 4);
  float4 b1 = *(const float4*)(b + 1024 + tid * 4);
  float4 o0, o1;
  o0.x = (v0.x - mu) * rstd * g0.x + b0.x;
  o0.y = (v0.y - mu) * rstd * g0.y + b0.y;
  o0.z = (v0.z - mu) * rstd * g0.z + b0.z;
  o0.w = (v0.w - mu) * rstd * g0.w + b0.w;
  o1.x = (v1.x - mu) * rstd * g1.x + b1.x;
  o1.y = (v1.y - mu) * rstd * g1.y + b1.y;
  o1.z = (v1.z - mu) * rstd * g1.z + b1.z;
  o1.w = (v1.w - mu) * rstd * g1.w + b1.w;
  *(float4*)(out + (size_t)row * E_DIM + tid * 4) = o0;
  *(float4*)(out + (size_t)row * E_DIM + 1024 + tid * 4) = o1;
}

extern "C" void kernel_launch(void* const* d_in, const int* in_sizes, int n_in,
                              void* d_out, int out_size, void* d_ws, size_t ws_size,
                              hipStream_t stream) {
  const float* query     = (const float*)d_in[0];
  const float* key       = (const float*)d_in[1];
  const float* value     = (const float*)d_in[2];
  const float* time_emb  = (const float*)d_in[3];
  const float* in_proj_w = (const float*)d_in[4];
  const float* in_proj_b = (const float*)d_in[5];
  const float* out_w     = (const float*)d_in[6];
  const float* out_b     = (const float*)d_in[7];
  const float* tp_w      = (const float*)d_in[8];
  const float* tp_b      = (const float*)d_in[9];
  const float* ln_g      = (const float*)d_in[10];
  const float* ln_b      = (const float*)d_in[11];

  char* ws = (char*)d_ws;
  unsigned short* qa   = (unsigned short*)(ws + 0);         //  8 MB bf16 query
  unsigned short* ka   = (unsigned short*)(ws + 8388608);   //  8 MB bf16 key
  unsigned short* va   = (unsigned short*)(ws + 16777216);  //  8 MB bf16 value
  unsigned short* wqkv = (unsigned short*)(ws + 25165824);  // 24 MB bf16 in_proj_w
  unsigned short* wo   = (unsigned short*)(ws + 50331648);  //  8 MB bf16 out_w
  unsigned short* qb   = (unsigned short*)(ws + 58720256);  //  8 MB bf16 Q proj
  unsigned short* kb   = (unsigned short*)(ws + 67108864);  //  8 MB bf16 K proj
  unsigned short* vt   = (unsigned short*)(ws + 75497472);  //  8 MB bf16 V^T proj
  float*          tb   = (float*)(ws + 83886080);           // 128 KB time bias
  // aliases (lifetimes disjoint on the serial stream):
  unsigned short* ctx  = wqkv;                              //  8 MB, after gemm<0> done with wqkv
  float*          xb   = (float*)(ws + 0);                  // 16 MB over qa+ka, after flash

  // 1) fp32 -> bf16 conversions
  convert_bf16<<<dim3(2048, 7), 256, 0, stream>>>(query, key, value, in_proj_w,
                                                  out_w, qa, ka, va, wqkv, wo);
  // 2) per-head time bias
  time_bias_kernel<<<512, 256, 0, stream>>>(time_emb, tp_w, tp_b, tb);
  // 3) QKV projection (z selects q/k/v; V stored transposed)
  gemm_bt<0><<<dim3(16, 16, 3), 256, 0, stream>>>(qa, ka, va, wqkv, in_proj_b,
                                                  qb, kb, vt, nullptr, nullptr);
  // 4) flash attention -> ctx (bf16)
  flash_attn<<<dim3(32, 16), 256, 0, stream>>>(qb, kb, vt, tb, ctx);
  // 5) out projection + residual -> xb (fp32)
  gemm_bt<1><<<dim3(16, 16, 1), 256, 0, stream>>>(ctx, nullptr, nullptr, wo,
                                                  out_b, nullptr, nullptr, nullptr,
                                                  query, xb);
  // 6) LayerNorm -> d_out
  layernorm_kernel<<<2048, 256, 0, stream>>>(xb, ln_g, ln_b, (float*)d_out);
}